// Round 12
// baseline (2986.839 us; speedup 1.0000x reference)
//
#include <hip/hip_runtime.h>
#include <math.h>

#define BATCH 32
#define LHIST 96
#define NVARS 862
#define LFUT  96
#define DMODEL 512
#define DINNER 512
#define DSTATE 32
#define DTRANK 32
#define SCAN_C 32
#define SCAN_TC ((NVARS + SCAN_C - 1) / SCAN_C)   // 27

typedef short short8 __attribute__((ext_vector_type(8)));
typedef float floatx4 __attribute__((ext_vector_type(4)));
typedef unsigned short ushort;

#define LOG2E 1.44269504088896f

static __device__ __forceinline__ ushort f2b(float f) {
    unsigned u = __builtin_bit_cast(unsigned, f);
    unsigned r = (u + 0x7FFFu + ((u >> 16) & 1u)) >> 16;
    return (ushort)r;
}
static __device__ __forceinline__ float b2f(ushort h) {
    unsigned u = ((unsigned)h) << 16;
    return __builtin_bit_cast(float, u);
}

// async global->LDS, 16B per lane. LDS dest semantics: wave-uniform base +
// lane*16 (m104); our mapping computes exactly that per-lane.
static __device__ __forceinline__ void load_lds16(const void* g, void* l) {
    __builtin_amdgcn_global_load_lds(
        (const __attribute__((address_space(1))) unsigned int*)g,
        (__attribute__((address_space(3))) unsigned int*)l, 16, 0, 0);
}

// ---------------------------------------------------------------- mean/std
__global__ void meanstd_k(const float* __restrict__ hist, ushort* __restrict__ xinb,
                          float* __restrict__ meanb, float* __restrict__ stdb,
                          int b0, int CB) {
    int idx = blockIdx.x * blockDim.x + threadIdx.x;
    if (idx >= CB * NVARS) return;
    int b = b0 + idx / NVARS, n = idx % NVARS;
    const float* p = hist + (size_t)b * LHIST * NVARS + n;
    float s = 0.f;
    for (int l = 0; l < LHIST; l++) s += p[(size_t)l * NVARS];
    float mean = s * (1.f / LHIST);
    float v = 0.f;
    for (int l = 0; l < LHIST; l++) { float d = p[(size_t)l * NVARS] - mean; v += d * d; }
    v *= (1.f / LHIST);
    float sd = sqrtf(v + 1e-5f);
    float inv = 1.f / sd;
    meanb[idx] = mean;
    stdb[idx]  = sd;
    ushort* o = xinb + (size_t)idx * LHIST;
    for (int l = 0; l < LHIST; l++) o[l] = f2b((p[(size_t)l * NVARS] - mean) * inv);
}

// ---------------------------------------------------------------- weight cast+transpose
// batched: W[P][K][N] -> Wt[P][N][K] bf16
__global__ void castT_k(const float* __restrict__ W, ushort* __restrict__ Wt,
                        int K, int N, int P) {
    size_t idx = (size_t)blockIdx.x * blockDim.x + threadIdx.x;
    if (idx >= (size_t)P * K * N) return;
    size_t kn = (size_t)K * N;
    int p = (int)(idx / kn);
    int rem = (int)(idx % kn);
    int k = rem / N, n = rem % N;
    Wt[(size_t)p * kn + (size_t)n * K + k] = f2b(W[idx]);
}

// ---------------------------------------------------------------- bf16 MFMA GEMM
// C[M,N] = act(A[M,K]bf16 @ Bt[N,K]^T + bias) (+C). act: 0 none, 1 relu, 2 softplus.
// Staging via global_load_lds width=16 (m97 ladder step: 517->874 TF).
#define TBM 128
#define TBN 128
#define TBK 32

__global__ __launch_bounds__(256)
void bgemm_k(const ushort* __restrict__ A, int lda,
             const ushort* __restrict__ Bt, int ldb,
             const float* __restrict__ bias,
             float* __restrict__ C, int ldc,
             ushort* __restrict__ C2, int ldc2,
             int M, int N, int K, int act, int accum) {
    __shared__ ushort As[TBM][TBK];
    __shared__ ushort Bs[TBN][TBK];
    int tid = threadIdx.x;
    int gm0 = blockIdx.y * TBM, gn0 = blockIdx.x * TBN;
    int lane = tid & 63, w = tid >> 6;
    int wm = (w >> 1) * 64, wn = (w & 1) * 64;
    int col16 = lane & 15, quad = lane >> 4;

    floatx4 acc[4][4];
#pragma unroll
    for (int i = 0; i < 4; i++)
#pragma unroll
        for (int j = 0; j < 4; j++) acc[i][j] = (floatx4){0.f, 0.f, 0.f, 0.f};

    int srow = tid >> 2;            // 0..63
    int schunk = (tid & 3) * 8;     // element offset in k (0,8,16,24)

    // loop-invariant row pointers (clamped edges)
    const ushort* pa0 = A + (size_t)min(gm0 + srow, M - 1) * lda + schunk;
    const ushort* pa1 = A + (size_t)min(gm0 + srow + 64, M - 1) * lda + schunk;
    const ushort* pb0 = Bt + (size_t)min(gn0 + srow, N - 1) * ldb + schunk;
    const ushort* pb1 = Bt + (size_t)min(gn0 + srow + 64, N - 1) * ldb + schunk;
    // lane-ordered LDS dests: byte offset tid*16 within each 64-row half
    ushort* la0 = &As[0][0] + (size_t)tid * 8;
    ushort* la1 = la0 + 2048;
    ushort* lb0 = &Bs[0][0] + (size_t)tid * 8;
    ushort* lb1 = lb0 + 2048;

    for (int k0 = 0; k0 < K; k0 += TBK) {
        __syncthreads();                       // prior ds_reads done
        load_lds16(pa0 + k0, la0);
        load_lds16(pa1 + k0, la1);
        load_lds16(pb0 + k0, lb0);
        load_lds16(pb1 + k0, lb1);
        __syncthreads();                       // compiler drains vmcnt here

        short8 af[4], bf[4];
#pragma unroll
        for (int mt = 0; mt < 4; mt++)
            af[mt] = *(const short8*)&As[wm + mt * 16 + col16][quad * 8];
#pragma unroll
        for (int nt = 0; nt < 4; nt++)
            bf[nt] = *(const short8*)&Bs[wn + nt * 16 + col16][quad * 8];
#pragma unroll
        for (int mt = 0; mt < 4; mt++)
#pragma unroll
            for (int nt = 0; nt < 4; nt++)
                acc[mt][nt] = __builtin_amdgcn_mfma_f32_16x16x32_bf16(
                    af[mt], bf[nt], acc[mt][nt], 0, 0, 0);
    }

    int rbase = gm0 + wm + quad * 4;
    int cbase = gn0 + wn + col16;
#pragma unroll
    for (int mt = 0; mt < 4; mt++) {
#pragma unroll
        for (int reg = 0; reg < 4; reg++) {
            int r = rbase + mt * 16 + reg;
            if (r >= M) continue;
#pragma unroll
            for (int nt = 0; nt < 4; nt++) {
                int c = cbase + nt * 16;
                if (c >= N) continue;
                float v = acc[mt][nt][reg];
                if (bias) v += bias[c];
                if (act == 1) v = fmaxf(v, 0.f);
                else if (act == 2) v = (v > 20.f) ? v : log1pf(expf(v));
                if (accum) v += C[(size_t)r * ldc + c];
                if (C)  C[(size_t)r * ldc + c] = v;
                if (C2) C2[(size_t)r * ldc2 + c] = f2b(v);
            }
        }
    }
}

// ---------------------------------------------------------------- conv+silu (bf16 in/out, x8)
__global__ void conv8_k(const ushort* __restrict__ uzb, const float* __restrict__ cw,
                        const float* __restrict__ cb, ushort* __restrict__ ucb,
                        int rev, int R) {
    int idx = blockIdx.x * blockDim.x + threadIdx.x;
    if (idx >= R * 64) return;
    int m = idx >> 6;
    int e0 = (idx & 63) * 8;
    int t = m % NVARS;
    const ushort* up = uzb + (size_t)m * 1024 + e0;
    short8 cur = *(const short8*)up;
    short8 oth = (short8){0,0,0,0,0,0,0,0};
    if (!rev) { if (t > 0)          oth = *(const short8*)(up - 1024); }
    else      { if (t < NVARS - 1)  oth = *(const short8*)(up + 1024); }
    short8 res;
#pragma unroll
    for (int i = 0; i < 8; i++) {
        int e = e0 + i;
        float v = cw[e * 2] * b2f((ushort)oth[i]) + cw[e * 2 + 1] * b2f((ushort)cur[i]) + cb[e];
        float sig = 1.f / (1.f + __expf(-v));
        res[i] = (short)f2b(v * sig);
    }
    *(short8*)(ucb + (size_t)m * 512 + e0) = res;
}

// ---------------------------------------------------------------- chunked scan
// delta bf16 in deltab, z bf16 in uzb[:,512:], u bf16 in ucb, B/C fp32 in xdbc.
// A_log = log(1..32) by construction -> A[s] = -(s+1): exp(d*A[s]) = q^(s+1),
// q = exp(-d). Fast path holds NO A registers; slow fallback recomputes A
// inline (never taken in practice).
// launch_bounds (256,4): (256,8) forced VGPR=32 and spilled h[32] (R10);
// (256,4) -> VGPR 64, no spill, 67.5us (R11).

static __device__ __forceinline__ bool a_is_fast(const float* A_log, int e) {
    bool f = true;
#pragma unroll
    for (int s = 0; s < DSTATE; s++) {
        float a = -__expf(A_log[e * DSTATE + s]);
        f = f && (fabsf(a + (float)(s + 1)) < 1e-3f * (s + 1));
    }
    return f;
}

// Pass A: local scan from h=0 -> Hpart[c][s][be], Sd[c][be]
__global__ __launch_bounds__(256, 4)
void scan_part_k(const ushort* __restrict__ deltab, const ushort* __restrict__ ucb,
                 const float* __restrict__ xdbc, const float* __restrict__ A_log,
                 float* __restrict__ Hpart, float* __restrict__ Sd,
                 int rev, int CB) {
    int NP = CB * DINNER;
    int idx = blockIdx.x * blockDim.x + threadIdx.x;
    if (idx >= NP * SCAN_C) return;
    int c = idx / NP, be = idx % NP;
    int b = be >> 9, e = be & (DINNER - 1);

    float h[DSTATE];
#pragma unroll
    for (int s = 0; s < DSTATE; s++) h[s] = 0.f;
    float sd = 0.f;
    int tau1 = min((c + 1) * SCAN_TC, NVARS);
    if (a_is_fast(A_log, e)) {
        for (int tau = c * SCAN_TC; tau < tau1; tau++) {
            int t = rev ? (NVARS - 1 - tau) : tau;
            size_t m = (size_t)b * NVARS + t;
            float d  = b2f(deltab[m * 512 + e]);
            float uv = b2f(ucb[m * 512 + e]);
            float du = d * uv;
            sd += d;
            const float4* Bp4 = (const float4*)(xdbc + m * 96 + DTRANK);
            float q = __expf(-d), pw = q;
#pragma unroll
            for (int g = 0; g < 8; g++) {
                float4 bv = Bp4[g];
                h[4*g+0] = pw * h[4*g+0] + du * bv.x; pw *= q;
                h[4*g+1] = pw * h[4*g+1] + du * bv.y; pw *= q;
                h[4*g+2] = pw * h[4*g+2] + du * bv.z; pw *= q;
                h[4*g+3] = pw * h[4*g+3] + du * bv.w; if (g < 7) pw *= q;
            }
        }
    } else {
        for (int tau = c * SCAN_TC; tau < tau1; tau++) {
            int t = rev ? (NVARS - 1 - tau) : tau;
            size_t m = (size_t)b * NVARS + t;
            float d  = b2f(deltab[m * 512 + e]);
            float uv = b2f(ucb[m * 512 + e]);
            float du = d * uv;
            sd += d;
            const float* Bp = xdbc + m * 96 + DTRANK;
#pragma unroll
            for (int s = 0; s < DSTATE; s++) {
                float a2 = -__expf(A_log[e * DSTATE + s]) * LOG2E;
                h[s] = exp2f(d * a2) * h[s] + du * Bp[s];
            }
        }
    }
    Sd[(size_t)c * NP + be] = sd;
#pragma unroll
    for (int s = 0; s < DSTATE; s++)
        Hpart[((size_t)c * DSTATE + s) * NP + be] = h[s];
}

// Pass B: thread per (s, be); carry across chunks; Hpart -> carry-in (in place).
__global__ __launch_bounds__(256)
void scan_carry_k(float* __restrict__ Hpart, const float* __restrict__ Sd,
                  const float* __restrict__ A_log, int CB) {
    int NP = CB * DINNER;
    int idx = blockIdx.x * blockDim.x + threadIdx.x;
    if (idx >= NP * DSTATE) return;
    int s = idx / NP, be = idx % NP;
    int e = be & (DINNER - 1);
    float a2 = -__expf(A_log[e * DSTATE + s]) * LOG2E;
    float carry = 0.f;
    for (int c = 0; c < SCAN_C; c++) {
        float sd = Sd[(size_t)c * NP + be];
        size_t off = ((size_t)c * DSTATE + s) * NP + be;
        float hp = Hpart[off];
        Hpart[off] = carry;
        carry = hp + exp2f(a2 * sd) * carry;
    }
}

// Pass C: rerun local scan seeded with carry-in; emit gated y as bf16.
__global__ __launch_bounds__(256, 4)
void scan_final_k(const ushort* __restrict__ deltab, const ushort* __restrict__ uzb,
                  const ushort* __restrict__ ucb, const float* __restrict__ xdbc,
                  const float* __restrict__ A_log, const float* __restrict__ Dp,
                  const float* __restrict__ CarryIn, ushort* __restrict__ yb,
                  int rev, int CB) {
    int NP = CB * DINNER;
    int idx = blockIdx.x * blockDim.x + threadIdx.x;
    if (idx >= NP * SCAN_C) return;
    int c = idx / NP, be = idx % NP;
    int b = be >> 9, e = be & (DINNER - 1);

    float h[DSTATE];
#pragma unroll
    for (int s = 0; s < DSTATE; s++)
        h[s] = CarryIn[((size_t)c * DSTATE + s) * NP + be];
    float Dv = Dp[e];
    int tau1 = min((c + 1) * SCAN_TC, NVARS);
    if (a_is_fast(A_log, e)) {
        for (int tau = c * SCAN_TC; tau < tau1; tau++) {
            int t = rev ? (NVARS - 1 - tau) : tau;
            size_t m = (size_t)b * NVARS + t;
            float d  = b2f(deltab[m * 512 + e]);
            float zz = b2f(uzb[m * 1024 + 512 + e]);
            float uv = b2f(ucb[m * 512 + e]);
            float du = d * uv;
            const float4* Bp4 = (const float4*)(xdbc + m * 96 + DTRANK);
            const float4* Cp4 = Bp4 + 8;
            float q = __expf(-d), pw = q;
            float accv = 0.f;
#pragma unroll
            for (int g = 0; g < 8; g++) {
                float4 bv = Bp4[g];
                float4 cv = Cp4[g];
                h[4*g+0] = pw * h[4*g+0] + du * bv.x; accv += h[4*g+0] * cv.x; pw *= q;
                h[4*g+1] = pw * h[4*g+1] + du * bv.y; accv += h[4*g+1] * cv.y; pw *= q;
                h[4*g+2] = pw * h[4*g+2] + du * bv.z; accv += h[4*g+2] * cv.z; pw *= q;
                h[4*g+3] = pw * h[4*g+3] + du * bv.w; accv += h[4*g+3] * cv.w;
                if (g < 7) pw *= q;
            }
            float sig = 1.f / (1.f + __expf(-zz));
            yb[m * 512 + e] = f2b((accv + uv * Dv) * (zz * sig));
        }
    } else {
        for (int tau = c * SCAN_TC; tau < tau1; tau++) {
            int t = rev ? (NVARS - 1 - tau) : tau;
            size_t m = (size_t)b * NVARS + t;
            float d  = b2f(deltab[m * 512 + e]);
            float zz = b2f(uzb[m * 1024 + 512 + e]);
            float uv = b2f(ucb[m * 512 + e]);
            float du = d * uv;
            const float* Bp = xdbc + m * 96 + DTRANK;
            const float* Cp = Bp + DSTATE;
            float accv = 0.f;
#pragma unroll
            for (int s = 0; s < DSTATE; s++) {
                float a2 = -__expf(A_log[e * DSTATE + s]) * LOG2E;
                h[s] = exp2f(d * a2) * h[s] + du * Bp[s];
                accv += h[s] * Cp[s];
            }
            float sig = 1.f / (1.f + __expf(-zz));
            yb[m * 512 + e] = f2b((accv + uv * Dv) * (zz * sig));
        }
    }
}

// ---------------------------------------------------------------- layernorm
__global__ __launch_bounds__(64)
void ln_k(const float* __restrict__ in1, const float* __restrict__ in2,
          const float* __restrict__ w, const float* __restrict__ b,
          float* __restrict__ out, ushort* __restrict__ outb) {
    int row = blockIdx.x;
    int lane = threadIdx.x;
    const float* p1 = in1 + (size_t)row * DMODEL;
    const float* p2 = in2 ? in2 + (size_t)row * DMODEL : nullptr;
    float v[8];
#pragma unroll
    for (int i = 0; i < 8; i++) {
        int c = lane + i * 64;
        v[i] = p1[c];
        if (p2) v[i] += p2[c];
    }
    float s = 0.f;
#pragma unroll
    for (int i = 0; i < 8; i++) s += v[i];
#pragma unroll
    for (int off = 32; off >= 1; off >>= 1) s += __shfl_xor(s, off);
    float mean = s * (1.f / DMODEL);
    float q = 0.f;
#pragma unroll
    for (int i = 0; i < 8; i++) { float d = v[i] - mean; q += d * d; }
#pragma unroll
    for (int off = 32; off >= 1; off >>= 1) q += __shfl_xor(q, off);
    float rs = rsqrtf(q * (1.f / DMODEL) + 1e-5f);
#pragma unroll
    for (int i = 0; i < 8; i++) {
        int c = lane + i * 64;
        float o = (v[i] - mean) * rs * w[c] + b[c];
        if (out)  out[(size_t)row * DMODEL + c] = o;
        if (outb) outb[(size_t)row * DMODEL + c] = f2b(o);
    }
}

// ---------------------------------------------------------------- de-norm + transpose
__global__ void final_k(const float* __restrict__ dec, const float* __restrict__ meanb,
                        const float* __restrict__ stdb, float* __restrict__ out,
                        int b0, int CB) {
    int idx = blockIdx.x * blockDim.x + threadIdx.x;
    if (idx >= CB * LFUT * NVARS) return;
    int n = idx % NVARS;
    int r = idx / NVARS;
    int l = r % LFUT;
    int bl = r / LFUT;
    int tok = bl * NVARS + n;
    out[(size_t)((b0 + bl) * LFUT + l) * NVARS + n] =
        dec[(size_t)tok * LFUT + l] * stdb[tok] + meanb[tok];
}

// ---------------------------------------------------------------- launch
extern "C" void kernel_launch(void* const* d_in, const int* in_sizes, int n_in,
                              void* d_out, int out_size, void* d_ws, size_t ws_size,
                              hipStream_t stream) {
    const float* hist    = (const float*)d_in[0];
    const float* emb_w   = (const float*)d_in[1];
    const float* emb_b   = (const float*)d_in[2];
    const float* m_in_w  = (const float*)d_in[3];
    const float* m_conv_w= (const float*)d_in[4];
    const float* m_conv_b= (const float*)d_in[5];
    const float* m_x_w   = (const float*)d_in[6];
    const float* m_dt_w  = (const float*)d_in[7];
    const float* m_dt_b  = (const float*)d_in[8];
    const float* m_A_log = (const float*)d_in[9];
    const float* m_D     = (const float*)d_in[10];
    const float* m_out_w = (const float*)d_in[11];
    const float* ffn_w1  = (const float*)d_in[12];
    const float* ffn_b1  = (const float*)d_in[13];
    const float* ffn_w2  = (const float*)d_in[14];
    const float* ffn_b2  = (const float*)d_in[15];
    const float* norm1_w = (const float*)d_in[16];
    const float* norm1_b = (const float*)d_in[17];
    const float* norm2_w = (const float*)d_in[18];
    const float* norm2_b = (const float*)d_in[19];
    const float* normf_w = (const float*)d_in[20];
    const float* normf_b = (const float*)d_in[21];
    const float* proj_w  = (const float*)d_in[22];
    const float* proj_b  = (const float*)d_in[23];

    float* out = (float*)d_out;
    float* ws  = (float*)d_ws;

    const size_t WTSE = 4u*1024*512 + 4u*512*512 + 2u*512*512 + 2u*512*512
                      + 96u*512 + 4u*96*512 + 4u*512*32 + 96u*512;

    // adaptive CB so footprint fits ws_size
    int CB = BATCH;
    for (;;) {
        size_t R = (size_t)CB * NVARS, NP = (size_t)CB * DINNER;
        size_t Rp = (R + 3) & ~3ull;
        size_t fl = R * 1120 + 2 * Rp + (size_t)SCAN_C * 33 * NP;   // fp32 elems
        size_t us = R * 3264 + WTSE;                                 // bf16 elems
        if (fl * 4 + us * 2 + 1024 <= ws_size || CB == 1) break;
        CB >>= 1;
    }
    const int R  = CB * NVARS;
    const int NP = CB * DINNER;
    const size_t Rp = ((size_t)R + 3) & ~3ull;

    float* x     = ws;                                    // [R][512]
    float* accb  = x + (size_t)R * 512;                   // [R][512]
    float* xdbc  = accb + (size_t)R * 512;                // [R][96]
    float* meanb = xdbc + (size_t)R * 96;                 // [Rp]
    float* stdb  = meanb + Rp;                            // [Rp]
    float* Hpart = stdb + Rp;                             // [C][32][NP]
    float* Sd    = Hpart + (size_t)SCAN_C * DSTATE * NP;  // [C][NP]
    ushort* xb     = (ushort*)(Sd + (size_t)SCAN_C * NP); // [R][512]
    ushort* ybmid  = xb + (size_t)R * 512;                // [R][512]
    ushort* ucb    = ybmid + (size_t)R * 512;             // [R][512]
    ushort* uzb    = ucb + (size_t)R * 512;               // [R][1024]
    ushort* deltab = uzb + (size_t)R * 1024;              // [R][512]
    ushort* xinb   = deltab + (size_t)R * 512;            // [R][96]
    ushort* xdbcb  = xinb + (size_t)R * 96;               // [R][96]
    ushort* wts    = xdbcb + (size_t)R * 96;

    ushort *inw_t, *outw_t, *f1_t, *f2_t, *emb_t, *xw_t, *dtw_t, *proj_t;
    {
        ushort* p = wts;
        inw_t  = p; p += (size_t)4 * 1024 * 512;
        outw_t = p; p += (size_t)4 * 512 * 512;
        f1_t   = p; p += (size_t)2 * 512 * 512;
        f2_t   = p; p += (size_t)2 * 512 * 512;
        emb_t  = p; p += (size_t)512 * 96;
        xw_t   = p; p += (size_t)4 * 96 * 512;
        dtw_t  = p; p += (size_t)4 * 512 * 32;
        proj_t = p;
    }

    // batched weight cast+transpose (8 dispatches)
    castT_k<<<(4 * 512 * 1024 + 255) / 256, 256, 0, stream>>>(m_in_w, inw_t, 512, 1024, 4);
    castT_k<<<(4 * 512 * 512 + 255) / 256, 256, 0, stream>>>(m_out_w, outw_t, 512, 512, 4);
    castT_k<<<(2 * 512 * 512 + 255) / 256, 256, 0, stream>>>(ffn_w1, f1_t, 512, 512, 2);
    castT_k<<<(2 * 512 * 512 + 255) / 256, 256, 0, stream>>>(ffn_w2, f2_t, 512, 512, 2);
    castT_k<<<(96 * 512 + 255) / 256, 256, 0, stream>>>(emb_w, emb_t, 96, 512, 1);
    castT_k<<<(4 * 512 * 96 + 255) / 256, 256, 0, stream>>>(m_x_w, xw_t, 512, 96, 4);
    castT_k<<<(4 * 32 * 512 + 255) / 256, 256, 0, stream>>>(m_dt_w, dtw_t, 32, 512, 4);
    castT_k<<<(512 * 96 + 255) / 256, 256, 0, stream>>>(proj_w, proj_t, 512, 96, 1);

    auto bgemm = [&](const ushort* A, int lda, const ushort* Bt, int ldb,
                     const float* bias, float* C, int ldc, ushort* C2, int ldc2,
                     int M, int N, int K, int act, int accum) {
        dim3 grid((N + TBN - 1) / TBN, (M + TBM - 1) / TBM);
        bgemm_k<<<grid, 256, 0, stream>>>(A, lda, Bt, ldb, bias, C, ldc, C2, ldc2,
                                          M, N, K, act, accum);
    };

    for (int b0 = 0; b0 < BATCH; b0 += CB) {
        meanstd_k<<<(R + 255) / 256, 256, 0, stream>>>(hist, xinb, meanb, stdb, b0, CB);
        bgemm(xinb, 96, emb_t, 96, emb_b, x, 512, xb, 512, R, 512, 96, 0, 0);

        for (int l = 0; l < 2; l++) {
            for (int dir = 0; dir < 2; dir++) {
                int p = l * 2 + dir;
                const float* cw   = m_conv_w + (size_t)p * DINNER * 2;
                const float* cb   = m_conv_b + (size_t)p * DINNER;
                const float* dtb  = m_dt_b  + (size_t)p * DINNER;
                const float* alog = m_A_log + (size_t)p * DINNER * DSTATE;
                const float* Dp   = m_D     + (size_t)p * DINNER;

                // uzb = bf16(x @ in_w)   [R][1024] (u | z)
                bgemm(xb, 512, inw_t + (size_t)p * 1024 * 512, 512, nullptr,
                      nullptr, 0, uzb, 1024, R, 1024, 512, 0, 0);
                // ucb = bf16(silu(conv(u)))
                conv8_k<<<(R * 64 + 255) / 256, 256, 0, stream>>>(uzb, cw, cb, ucb, dir, R);
                // xdbc = uc @ x_w  (fp32 B/C for scan + bf16 dt for dt-proj)
                bgemm(ucb, 512, xw_t + (size_t)p * 96 * 512, 512, nullptr,
                      xdbc, 96, xdbcb, 96, R, 96, 512, 0, 0);
                // deltab = bf16(softplus(dt @ dt_w + dt_b))
                bgemm(xdbcb, 96, dtw_t + (size_t)p * 512 * 32, 32, dtb,
                      nullptr, 0, deltab, 512, R, 512, 32, 2, 0);
                // chunked scan
                scan_part_k<<<(NP * SCAN_C + 255) / 256, 256, 0, stream>>>(
                    deltab, ucb, xdbc, alog, Hpart, Sd, dir, CB);
                scan_carry_k<<<(NP * DSTATE + 255) / 256, 256, 0, stream>>>(
                    Hpart, Sd, alog, CB);
                scan_final_k<<<(NP * SCAN_C + 255) / 256, 256, 0, stream>>>(
                    deltab, uzb, ucb, xdbc, alog, Dp, Hpart, ybmid, dir, CB);
                // acc (=)+= y @ out_w
                bgemm(ybmid, 512, outw_t + (size_t)p * 512 * 512, 512, nullptr,
                      accb, 512, nullptr, 0, R, 512, 512, 0, dir);
            }
            ln_k<<<R, 64, 0, stream>>>(accb, x, norm1_w + l * DMODEL, norm1_b + l * DMODEL,
                                       x, xb);
            bgemm(xb, 512, f1_t + (size_t)l * 512 * 512, 512, ffn_b1 + l * DMODEL,
                  nullptr, 0, ybmid, 512, R, 512, 512, 1, 0);
            bgemm(ybmid, 512, f2_t + (size_t)l * 512 * 512, 512, ffn_b2 + l * DMODEL,
                  accb, 512, nullptr, 0, R, 512, 512, 0, 0);
            ln_k<<<R, 64, 0, stream>>>(x, accb, norm2_w + l * DMODEL, norm2_b + l * DMODEL,
                                       x, xb);
        }

        ln_k<<<R, 64, 0, stream>>>(x, nullptr, normf_w, normf_b, nullptr, xb);
        bgemm(xb, 512, proj_t, 512, proj_b, xdbc, 96, nullptr, 0, R, 96, 512, 0, 0);
        final_k<<<(CB * LFUT * NVARS + 255) / 256, 256, 0, stream>>>(
            xdbc, meanb, stdb, out, b0, CB);
    }
}

// Round 13
// 2531.216 us; speedup vs baseline: 1.1800x; 1.1800x over previous
//
#include <hip/hip_runtime.h>
#include <math.h>

#define BATCH 32
#define LHIST 96
#define NVARS 862
#define LFUT  96
#define DMODEL 512
#define DINNER 512
#define DSTATE 32
#define DTRANK 32
#define SCAN_C 16
#define SCAN_TC ((NVARS + SCAN_C - 1) / SCAN_C)   // 54

typedef short short8 __attribute__((ext_vector_type(8)));
typedef float floatx4 __attribute__((ext_vector_type(4)));
typedef unsigned short ushort;

#define LOG2E 1.44269504088896f

static __device__ __forceinline__ ushort f2b(float f) {
    unsigned u = __builtin_bit_cast(unsigned, f);
    unsigned r = (u + 0x7FFFu + ((u >> 16) & 1u)) >> 16;
    return (ushort)r;
}
static __device__ __forceinline__ float b2f(ushort h) {
    unsigned u = ((unsigned)h) << 16;
    return __builtin_bit_cast(float, u);
}

// ---------------------------------------------------------------- mean/std
__global__ void meanstd_k(const float* __restrict__ hist, ushort* __restrict__ xinb,
                          float* __restrict__ meanb, float* __restrict__ stdb,
                          int b0, int CB) {
    int idx = blockIdx.x * blockDim.x + threadIdx.x;
    if (idx >= CB * NVARS) return;
    int b = b0 + idx / NVARS, n = idx % NVARS;
    const float* p = hist + (size_t)b * LHIST * NVARS + n;
    float s = 0.f;
    for (int l = 0; l < LHIST; l++) s += p[(size_t)l * NVARS];
    float mean = s * (1.f / LHIST);
    float v = 0.f;
    for (int l = 0; l < LHIST; l++) { float d = p[(size_t)l * NVARS] - mean; v += d * d; }
    v *= (1.f / LHIST);
    float sd = sqrtf(v + 1e-5f);
    float inv = 1.f / sd;
    meanb[idx] = mean;
    stdb[idx]  = sd;
    ushort* o = xinb + (size_t)idx * LHIST;
    for (int l = 0; l < LHIST; l++) o[l] = f2b((p[(size_t)l * NVARS] - mean) * inv);
}

// ---------------------------------------------------------------- weight casts
// batched: W[P][K][N] -> Wt[P][N][K] bf16
__global__ void castT_k(const float* __restrict__ W, ushort* __restrict__ Wt,
                        int K, int N, int P) {
    size_t idx = (size_t)blockIdx.x * blockDim.x + threadIdx.x;
    if (idx >= (size_t)P * K * N) return;
    size_t kn = (size_t)K * N;
    int p = (int)(idx / kn);
    int rem = (int)(idx % kn);
    int k = rem / N, n = rem % N;
    Wt[(size_t)p * kn + (size_t)n * K + k] = f2b(W[idx]);
}

// fused-direction x-proj weights: xw2[l][n:192][k:1024], block-diagonal
__global__ void xw2_cast(const float* __restrict__ xw, ushort* __restrict__ o) {
    int idx = blockIdx.x * blockDim.x + threadIdx.x;
    if (idx >= 2 * 192 * 1024) return;
    int l = idx / (192 * 1024);
    int r = idx % (192 * 1024);
    int n = r / 1024, k = r % 1024;
    int half = (n >= 96);
    int nn = n - 96 * half;
    float v = 0.f;
    if ((k >> 9) == half)
        v = xw[((size_t)(l * 2 + half) * 512 + (k & 511)) * 96 + nn];
    o[idx] = f2b(v);
}

// fused-direction dt-proj weights: dtw2[l][n:1024][k:192], block-diagonal
__global__ void dtw2_cast(const float* __restrict__ dtw, ushort* __restrict__ o) {
    int idx = blockIdx.x * blockDim.x + threadIdx.x;
    if (idx >= 2 * 1024 * 192) return;
    int l = idx / (1024 * 192);
    int r = idx % (1024 * 192);
    int n = r / 192, k = r % 192;
    int half = n >> 9;
    int nn = n & 511;
    int kb = k - 96 * half;
    float v = 0.f;
    if (kb >= 0 && kb < 32)
        v = dtw[((size_t)(l * 2 + half) * 32 + kb) * 512 + nn];
    o[idx] = f2b(v);
}

// fused-direction out-proj weights: outw2[l][n:512][k:1024] (K-concat fwd|rev)
__global__ void outw2_cast(const float* __restrict__ ow, ushort* __restrict__ o) {
    int idx = blockIdx.x * blockDim.x + threadIdx.x;
    if (idx >= 2 * 512 * 1024) return;
    int l = idx / (512 * 1024);
    int r = idx % (512 * 1024);
    int n = r / 1024, k = r % 1024;
    int half = k >> 9;
    float v = ow[((size_t)(l * 2 + half) * 512 + (k & 511)) * 512 + n];
    o[idx] = f2b(v);
}

// ---------------------------------------------------------------- bf16 MFMA GEMM
// C[M,N] = act(A[M,K]bf16 @ Bt[N,K]^T + bias) (+C). act: 0 none, 1 relu, 2 softplus.
// R11 form: register staging, loads issued before first barrier (overlaps with
// previous tile's MFMA). R12's global_load_lds between barriers was NEUTRAL/worse.
#define TBM 128
#define TBN 128
#define TBK 32

__global__ __launch_bounds__(256)
void bgemm_k(const ushort* __restrict__ A, int lda,
             const ushort* __restrict__ Bt, int ldb,
             const float* __restrict__ bias,
             float* __restrict__ C, int ldc,
             ushort* __restrict__ C2, int ldc2,
             int M, int N, int K, int act, int accum) {
    __shared__ ushort As[TBM][TBK];
    __shared__ ushort Bs[TBN][TBK];
    int tid = threadIdx.x;
    int gm0 = blockIdx.y * TBM, gn0 = blockIdx.x * TBN;
    int lane = tid & 63, w = tid >> 6;
    int wm = (w >> 1) * 64, wn = (w & 1) * 64;
    int col16 = lane & 15, quad = lane >> 4;

    floatx4 acc[4][4];
#pragma unroll
    for (int i = 0; i < 4; i++)
#pragma unroll
        for (int j = 0; j < 4; j++) acc[i][j] = (floatx4){0.f, 0.f, 0.f, 0.f};

    int srow = tid >> 2;
    int schunk = (tid & 3) * 8;

    for (int k0 = 0; k0 < K; k0 += TBK) {
        int ra0 = min(gm0 + srow, M - 1);
        int ra1 = min(gm0 + srow + 64, M - 1);
        short8 a0 = *(const short8*)(A + (size_t)ra0 * lda + k0 + schunk);
        short8 a1 = *(const short8*)(A + (size_t)ra1 * lda + k0 + schunk);
        int rb0 = min(gn0 + srow, N - 1);
        int rb1 = min(gn0 + srow + 64, N - 1);
        short8 b0 = *(const short8*)(Bt + (size_t)rb0 * ldb + k0 + schunk);
        short8 b1 = *(const short8*)(Bt + (size_t)rb1 * ldb + k0 + schunk);
        __syncthreads();
        *(short8*)&As[srow][schunk]      = a0;
        *(short8*)&As[srow + 64][schunk] = a1;
        *(short8*)&Bs[srow][schunk]      = b0;
        *(short8*)&Bs[srow + 64][schunk] = b1;
        __syncthreads();

        short8 af[4], bf[4];
#pragma unroll
        for (int mt = 0; mt < 4; mt++)
            af[mt] = *(const short8*)&As[wm + mt * 16 + col16][quad * 8];
#pragma unroll
        for (int nt = 0; nt < 4; nt++)
            bf[nt] = *(const short8*)&Bs[wn + nt * 16 + col16][quad * 8];
#pragma unroll
        for (int mt = 0; mt < 4; mt++)
#pragma unroll
            for (int nt = 0; nt < 4; nt++)
                acc[mt][nt] = __builtin_amdgcn_mfma_f32_16x16x32_bf16(
                    af[mt], bf[nt], acc[mt][nt], 0, 0, 0);
    }

    int rbase = gm0 + wm + quad * 4;
    int cbase = gn0 + wn + col16;
#pragma unroll
    for (int mt = 0; mt < 4; mt++) {
#pragma unroll
        for (int reg = 0; reg < 4; reg++) {
            int r = rbase + mt * 16 + reg;
            if (r >= M) continue;
#pragma unroll
            for (int nt = 0; nt < 4; nt++) {
                int c = cbase + nt * 16;
                if (c >= N) continue;
                float v = acc[mt][nt][reg];
                if (bias) v += bias[c];
                if (act == 1) v = fmaxf(v, 0.f);
                else if (act == 2) v = (v > 20.f) ? v : log1pf(expf(v));
                if (accum) v += C[(size_t)r * ldc + c];
                if (C)  C[(size_t)r * ldc + c] = v;
                if (C2) C2[(size_t)r * ldc2 + c] = f2b(v);
            }
        }
    }
}

// ---------------------------------------------------------------- conv+silu, both dirs
// uzb2 row: [u_f(512) | z_f(512) | u_r(512) | z_r(512)]. Writes ucb2 [R][1024]
// (col = half*512+e). rev = half.
__global__ void conv8_k(const ushort* __restrict__ uzb2, const float* __restrict__ cw2,
                        const float* __restrict__ cb2, ushort* __restrict__ ucb2, int R) {
    int idx = blockIdx.x * blockDim.x + threadIdx.x;
    if (idx >= R * 128) return;
    int m = idx >> 7;
    int c8 = (idx & 127) * 8;
    int half = c8 >> 9;
    int e0 = c8 & 511;
    int t = m % NVARS;
    const ushort* up = uzb2 + (size_t)m * 2048 + half * 1024 + e0;
    short8 cur = *(const short8*)up;
    short8 oth = (short8){0,0,0,0,0,0,0,0};
    if (!half) { if (t > 0)          oth = *(const short8*)(up - 2048); }
    else       { if (t < NVARS - 1)  oth = *(const short8*)(up + 2048); }
    const float* cw = cw2 + half * 1024;
    const float* cb = cb2 + half * 512;
    short8 res;
#pragma unroll
    for (int i = 0; i < 8; i++) {
        int e = e0 + i;
        float v = cw[e * 2] * b2f((ushort)oth[i]) + cw[e * 2 + 1] * b2f((ushort)cur[i]) + cb[e];
        float sig = 1.f / (1.f + __expf(-v));
        res[i] = (short)f2b(v * sig);
    }
    *(short8*)(ucb2 + (size_t)m * 1024 + c8) = res;
}

// ---------------------------------------------------------------- chunked scan, both dirs
// col in [0,1024): half = col>>9 (= rev direction, wave-uniform), e = col&511.
// delta bf16 deltab2[R][1024], u bf16 ucb2[R][1024], z in uzb2, B/C fp32 in
// xdbc2[R][192] (+half*96). A_log/D tables indexed by col via alog2 = A_log+l*2*512*32.
// Fast path: A[s] = -(s+1) (A_log = log(1..32) by construction), q=exp(-d),
// single power chain, NO A registers. launch_bounds (256,4): (256,8) forced
// VGPR=32 + h[32] spill (R10); (256,4) -> VGPR 64 no spill (R11).

static __device__ __forceinline__ bool a_is_fast(const float* A_log2, int col) {
    bool f = true;
#pragma unroll
    for (int s = 0; s < DSTATE; s++) {
        float a = -__expf(A_log2[col * DSTATE + s]);
        f = f && (fabsf(a + (float)(s + 1)) < 1e-3f * (s + 1));
    }
    return f;
}

// Pass A: local scan from h=0 -> Hpart[c][s][be], Sd[c][be]
__global__ __launch_bounds__(256, 4)
void scan_part_k(const ushort* __restrict__ deltab2, const ushort* __restrict__ ucb2,
                 const float* __restrict__ xdbc2, const float* __restrict__ alog2,
                 float* __restrict__ Hpart, float* __restrict__ Sd, int CB) {
    int NP2 = CB * 1024;
    int idx = blockIdx.x * blockDim.x + threadIdx.x;
    if (idx >= NP2 * SCAN_C) return;
    int c = idx / NP2, be = idx % NP2;
    int b = be >> 10, col = be & 1023;
    int rv = col >> 9;

    float h[DSTATE];
#pragma unroll
    for (int s = 0; s < DSTATE; s++) h[s] = 0.f;
    float sd = 0.f;
    int tau1 = min((c + 1) * SCAN_TC, NVARS);
    if (a_is_fast(alog2, col)) {
        for (int tau = c * SCAN_TC; tau < tau1; tau++) {
            int t = rv ? (NVARS - 1 - tau) : tau;
            size_t m = (size_t)b * NVARS + t;
            float d  = b2f(deltab2[m * 1024 + col]);
            float uv = b2f(ucb2[m * 1024 + col]);
            float du = d * uv;
            sd += d;
            const float4* Bp4 = (const float4*)(xdbc2 + m * 192 + rv * 96 + DTRANK);
            float q = __expf(-d), pw = q;
#pragma unroll
            for (int g = 0; g < 8; g++) {
                float4 bv = Bp4[g];
                h[4*g+0] = pw * h[4*g+0] + du * bv.x; pw *= q;
                h[4*g+1] = pw * h[4*g+1] + du * bv.y; pw *= q;
                h[4*g+2] = pw * h[4*g+2] + du * bv.z; pw *= q;
                h[4*g+3] = pw * h[4*g+3] + du * bv.w; if (g < 7) pw *= q;
            }
        }
    } else {
        for (int tau = c * SCAN_TC; tau < tau1; tau++) {
            int t = rv ? (NVARS - 1 - tau) : tau;
            size_t m = (size_t)b * NVARS + t;
            float d  = b2f(deltab2[m * 1024 + col]);
            float uv = b2f(ucb2[m * 1024 + col]);
            float du = d * uv;
            sd += d;
            const float* Bp = xdbc2 + m * 192 + rv * 96 + DTRANK;
#pragma unroll
            for (int s = 0; s < DSTATE; s++) {
                float a2 = -__expf(alog2[col * DSTATE + s]) * LOG2E;
                h[s] = exp2f(d * a2) * h[s] + du * Bp[s];
            }
        }
    }
    Sd[(size_t)c * NP2 + be] = sd;
#pragma unroll
    for (int s = 0; s < DSTATE; s++)
        Hpart[((size_t)c * DSTATE + s) * NP2 + be] = h[s];
}

// Pass B: thread per (s, be); carry across chunks; Hpart -> carry-in (in place).
__global__ __launch_bounds__(256)
void scan_carry_k(float* __restrict__ Hpart, const float* __restrict__ Sd,
                  const float* __restrict__ alog2, int CB) {
    int NP2 = CB * 1024;
    int idx = blockIdx.x * blockDim.x + threadIdx.x;
    if (idx >= NP2 * DSTATE) return;
    int s = idx / NP2, be = idx % NP2;
    int col = be & 1023;
    float a2 = -__expf(alog2[col * DSTATE + s]) * LOG2E;
    float carry = 0.f;
    for (int c = 0; c < SCAN_C; c++) {
        float sd = Sd[(size_t)c * NP2 + be];
        size_t off = ((size_t)c * DSTATE + s) * NP2 + be;
        float hp = Hpart[off];
        Hpart[off] = carry;
        carry = hp + exp2f(a2 * sd) * carry;
    }
}

// Pass C: rerun local scan seeded with carry-in; emit gated y as bf16.
// yb may alias deltab2 (same-element read-before-write, chunk-disjoint m).
__global__ __launch_bounds__(256, 4)
void scan_final_k(const ushort* __restrict__ deltab2, const ushort* __restrict__ uzb2,
                  const ushort* __restrict__ ucb2, const float* __restrict__ xdbc2,
                  const float* __restrict__ alog2, const float* __restrict__ Dp2,
                  const float* __restrict__ CarryIn, ushort* __restrict__ yb, int CB) {
    int NP2 = CB * 1024;
    int idx = blockIdx.x * blockDim.x + threadIdx.x;
    if (idx >= NP2 * SCAN_C) return;
    int c = idx / NP2, be = idx % NP2;
    int b = be >> 10, col = be & 1023;
    int rv = col >> 9;

    float h[DSTATE];
#pragma unroll
    for (int s = 0; s < DSTATE; s++)
        h[s] = CarryIn[((size_t)c * DSTATE + s) * NP2 + be];
    float Dv = Dp2[col];
    int tau1 = min((c + 1) * SCAN_TC, NVARS);
    if (a_is_fast(alog2, col)) {
        for (int tau = c * SCAN_TC; tau < tau1; tau++) {
            int t = rv ? (NVARS - 1 - tau) : tau;
            size_t m = (size_t)b * NVARS + t;
            float d  = b2f(deltab2[m * 1024 + col]);
            float zz = b2f(uzb2[m * 2048 + rv * 1024 + 512 + (col & 511)]);
            float uv = b2f(ucb2[m * 1024 + col]);
            float du = d * uv;
            const float4* Bp4 = (const float4*)(xdbc2 + m * 192 + rv * 96 + DTRANK);
            const float4* Cp4 = Bp4 + 8;
            float q = __expf(-d), pw = q;
            float accv = 0.f;
#pragma unroll
            for (int g = 0; g < 8; g++) {
                float4 bv = Bp4[g];
                float4 cv = Cp4[g];
                h[4*g+0] = pw * h[4*g+0] + du * bv.x; accv += h[4*g+0] * cv.x; pw *= q;
                h[4*g+1] = pw * h[4*g+1] + du * bv.y; accv += h[4*g+1] * cv.y; pw *= q;
                h[4*g+2] = pw * h[4*g+2] + du * bv.z; accv += h[4*g+2] * cv.z; pw *= q;
                h[4*g+3] = pw * h[4*g+3] + du * bv.w; accv += h[4*g+3] * cv.w;
                if (g < 7) pw *= q;
            }
            float sig = 1.f / (1.f + __expf(-zz));
            yb[m * 1024 + col] = f2b((accv + uv * Dv) * (zz * sig));
        }
    } else {
        for (int tau = c * SCAN_TC; tau < tau1; tau++) {
            int t = rv ? (NVARS - 1 - tau) : tau;
            size_t m = (size_t)b * NVARS + t;
            float d  = b2f(deltab2[m * 1024 + col]);
            float zz = b2f(uzb2[m * 2048 + rv * 1024 + 512 + (col & 511)]);
            float uv = b2f(ucb2[m * 1024 + col]);
            float du = d * uv;
            const float* Bp = xdbc2 + m * 192 + rv * 96 + DTRANK;
            const float* Cp = Bp + DSTATE;
            float accv = 0.f;
#pragma unroll
            for (int s = 0; s < DSTATE; s++) {
                float a2 = -__expf(alog2[col * DSTATE + s]) * LOG2E;
                h[s] = exp2f(d * a2) * h[s] + du * Bp[s];
                accv += h[s] * Cp[s];
            }
            float sig = 1.f / (1.f + __expf(-zz));
            yb[m * 1024 + col] = f2b((accv + uv * Dv) * (zz * sig));
        }
    }
}

// ---------------------------------------------------------------- layernorm
__global__ __launch_bounds__(64)
void ln_k(const float* __restrict__ in1, const float* __restrict__ in2,
          const float* __restrict__ w, const float* __restrict__ b,
          float* __restrict__ out, ushort* __restrict__ outb) {
    int row = blockIdx.x;
    int lane = threadIdx.x;
    const float* p1 = in1 + (size_t)row * DMODEL;
    const float* p2 = in2 ? in2 + (size_t)row * DMODEL : nullptr;
    float v[8];
#pragma unroll
    for (int i = 0; i < 8; i++) {
        int c = lane + i * 64;
        v[i] = p1[c];
        if (p2) v[i] += p2[c];
    }
    float s = 0.f;
#pragma unroll
    for (int i = 0; i < 8; i++) s += v[i];
#pragma unroll
    for (int off = 32; off >= 1; off >>= 1) s += __shfl_xor(s, off);
    float mean = s * (1.f / DMODEL);
    float q = 0.f;
#pragma unroll
    for (int i = 0; i < 8; i++) { float d = v[i] - mean; q += d * d; }
#pragma unroll
    for (int off = 32; off >= 1; off >>= 1) q += __shfl_xor(q, off);
    float rs = rsqrtf(q * (1.f / DMODEL) + 1e-5f);
#pragma unroll
    for (int i = 0; i < 8; i++) {
        int c = lane + i * 64;
        float o = (v[i] - mean) * rs * w[c] + b[c];
        if (out)  out[(size_t)row * DMODEL + c] = o;
        if (outb) outb[(size_t)row * DMODEL + c] = f2b(o);
    }
}

// ---------------------------------------------------------------- de-norm + transpose
__global__ void final_k(const float* __restrict__ dec, const float* __restrict__ meanb,
                        const float* __restrict__ stdb, float* __restrict__ out,
                        int b0, int CB) {
    int idx = blockIdx.x * blockDim.x + threadIdx.x;
    if (idx >= CB * LFUT * NVARS) return;
    int n = idx % NVARS;
    int r = idx / NVARS;
    int l = r % LFUT;
    int bl = r / LFUT;
    int tok = bl * NVARS + n;
    out[(size_t)((b0 + bl) * LFUT + l) * NVARS + n] =
        dec[(size_t)tok * LFUT + l] * stdb[tok] + meanb[tok];
}

// ---------------------------------------------------------------- launch
extern "C" void kernel_launch(void* const* d_in, const int* in_sizes, int n_in,
                              void* d_out, int out_size, void* d_ws, size_t ws_size,
                              hipStream_t stream) {
    const float* hist    = (const float*)d_in[0];
    const float* emb_w   = (const float*)d_in[1];
    const float* emb_b   = (const float*)d_in[2];
    const float* m_in_w  = (const float*)d_in[3];
    const float* m_conv_w= (const float*)d_in[4];
    const float* m_conv_b= (const float*)d_in[5];
    const float* m_x_w   = (const float*)d_in[6];
    const float* m_dt_w  = (const float*)d_in[7];
    const float* m_dt_b  = (const float*)d_in[8];
    const float* m_A_log = (const float*)d_in[9];
    const float* m_D     = (const float*)d_in[10];
    const float* m_out_w = (const float*)d_in[11];
    const float* ffn_w1  = (const float*)d_in[12];
    const float* ffn_b1  = (const float*)d_in[13];
    const float* ffn_w2  = (const float*)d_in[14];
    const float* ffn_b2  = (const float*)d_in[15];
    const float* norm1_w = (const float*)d_in[16];
    const float* norm1_b = (const float*)d_in[17];
    const float* norm2_w = (const float*)d_in[18];
    const float* norm2_b = (const float*)d_in[19];
    const float* normf_w = (const float*)d_in[20];
    const float* normf_b = (const float*)d_in[21];
    const float* proj_w  = (const float*)d_in[22];
    const float* proj_b  = (const float*)d_in[23];

    float* out = (float*)d_out;
    float* ws  = (float*)d_ws;

    // bf16 weight pool elems
    const size_t WTSE = 4u*1024*512      // in_w
                      + 2u*512*1024      // outw2 (K-concat)
                      + 2u*512*512 + 2u*512*512   // ffn1/ffn2
                      + 512u*96          // emb
                      + 2u*192*1024      // xw2 (block-diag)
                      + 2u*1024*192      // dtw2 (block-diag)
                      + 512u*96;         // proj

    // adaptive CB so footprint fits ws_size
    int CB = BATCH;
    for (;;) {
        size_t R = (size_t)CB * NVARS, NP2 = (size_t)CB * 1024;
        size_t Rp = (R + 3) & ~3ull;
        size_t fl = R * 1216 + 2 * Rp + (size_t)SCAN_C * 33 * NP2;  // fp32 elems
        size_t us = R * 4896 + WTSE;                                 // bf16 elems
        if (fl * 4 + us * 2 + 1024 <= ws_size || CB == 1) break;
        CB >>= 1;
    }
    const int R   = CB * NVARS;
    const int NP2 = CB * 1024;
    const size_t Rp = ((size_t)R + 3) & ~3ull;

    float* x     = ws;                                     // [R][512]
    float* accb  = x + (size_t)R * 512;                    // [R][512]
    float* xdbc2 = accb + (size_t)R * 512;                 // [R][192] (later dec[R][96])
    float* meanb = xdbc2 + (size_t)R * 192;                // [Rp]
    float* stdb  = meanb + Rp;                             // [Rp]
    float* Hpart = stdb + Rp;                              // [C][32][NP2]
    float* Sd    = Hpart + (size_t)SCAN_C * DSTATE * NP2;  // [C][NP2]
    ushort* xb      = (ushort*)(Sd + (size_t)SCAN_C * NP2); // [R][512]
    ushort* uzb2    = xb + (size_t)R * 512;                 // [R][2048]
    ushort* ucb2    = uzb2 + (size_t)R * 2048;              // [R][1024] (ffn-mid reuse)
    ushort* deltab2 = ucb2 + (size_t)R * 1024;              // [R][1024] (y2 aliased)
    ushort* xinb    = deltab2 + (size_t)R * 1024;           // [R][96]
    ushort* xdbc2b  = xinb + (size_t)R * 96;                // [R][192]
    ushort* wts     = xdbc2b + (size_t)R * 192;

    ushort *inw_t, *outw2_t, *f1_t, *f2_t, *emb_t, *xw2_t, *dtw2_t, *proj_t;
    {
        ushort* p = wts;
        inw_t   = p; p += (size_t)4 * 1024 * 512;
        outw2_t = p; p += (size_t)2 * 512 * 1024;
        f1_t    = p; p += (size_t)2 * 512 * 512;
        f2_t    = p; p += (size_t)2 * 512 * 512;
        emb_t   = p; p += (size_t)512 * 96;
        xw2_t   = p; p += (size_t)2 * 192 * 1024;
        dtw2_t  = p; p += (size_t)2 * 1024 * 192;
        proj_t  = p;
    }

    // weight casts (8 dispatches)
    castT_k<<<(4 * 512 * 1024 + 255) / 256, 256, 0, stream>>>(m_in_w, inw_t, 512, 1024, 4);
    outw2_cast<<<(2 * 512 * 1024 + 255) / 256, 256, 0, stream>>>(m_out_w, outw2_t);
    castT_k<<<(2 * 512 * 512 + 255) / 256, 256, 0, stream>>>(ffn_w1, f1_t, 512, 512, 2);
    castT_k<<<(2 * 512 * 512 + 255) / 256, 256, 0, stream>>>(ffn_w2, f2_t, 512, 512, 2);
    castT_k<<<(96 * 512 + 255) / 256, 256, 0, stream>>>(emb_w, emb_t, 96, 512, 1);
    xw2_cast<<<(2 * 192 * 1024 + 255) / 256, 256, 0, stream>>>(m_x_w, xw2_t);
    dtw2_cast<<<(2 * 1024 * 192 + 255) / 256, 256, 0, stream>>>(m_dt_w, dtw2_t);
    castT_k<<<(512 * 96 + 255) / 256, 256, 0, stream>>>(proj_w, proj_t, 512, 96, 1);

    auto bgemm = [&](const ushort* A, int lda, const ushort* Bt, int ldb,
                     const float* bias, float* C, int ldc, ushort* C2, int ldc2,
                     int M, int N, int K, int act, int accum) {
        dim3 grid((N + TBN - 1) / TBN, (M + TBM - 1) / TBM);
        bgemm_k<<<grid, 256, 0, stream>>>(A, lda, Bt, ldb, bias, C, ldc, C2, ldc2,
                                          M, N, K, act, accum);
    };

    for (int b0 = 0; b0 < BATCH; b0 += CB) {
        meanstd_k<<<(R + 255) / 256, 256, 0, stream>>>(hist, xinb, meanb, stdb, b0, CB);
        bgemm(xinb, 96, emb_t, 96, emb_b, x, 512, xb, 512, R, 512, 96, 0, 0);

        for (int l = 0; l < 2; l++) {
            const float* cw2   = m_conv_w + (size_t)l * 2048;        // [2][512][2]
            const float* cb2   = m_conv_b + (size_t)l * 1024;        // [2][512]
            const float* dtb2  = m_dt_b  + (size_t)l * 1024;         // [2][512]
            const float* alog2 = m_A_log + (size_t)l * 2 * 512 * 32; // [1024][32]
            const float* Dp2   = m_D     + (size_t)l * 1024;         // [1024]

            // uzb2 = bf16(x @ [in_w_f | in_w_r])   [R][2048]
            bgemm(xb, 512, inw_t + (size_t)(2 * l) * 1024 * 512, 512, nullptr,
                  nullptr, 0, uzb2, 2048, R, 2048, 512, 0, 0);
            // ucb2 = bf16(silu(conv(u))), both directions
            conv8_k<<<(R * 128 + 255) / 256, 256, 0, stream>>>(uzb2, cw2, cb2, ucb2, R);
            // xdbc2 = ucb2 @ xw2 (block-diag), fp32 + bf16
            bgemm(ucb2, 1024, xw2_t + (size_t)l * 192 * 1024, 1024, nullptr,
                  xdbc2, 192, xdbc2b, 192, R, 192, 1024, 0, 0);
            // deltab2 = bf16(softplus(xdbc2b @ dtw2 + dtb2)), both dirs
            bgemm(xdbc2b, 192, dtw2_t + (size_t)l * 1024 * 192, 192, dtb2,
                  nullptr, 0, deltab2, 1024, R, 1024, 192, 2, 0);
            // chunked scan, both dirs (y2 aliases deltab2)
            scan_part_k<<<(NP2 * SCAN_C + 255) / 256, 256, 0, stream>>>(
                deltab2, ucb2, xdbc2, alog2, Hpart, Sd, CB);
            scan_carry_k<<<(NP2 * DSTATE + 255) / 256, 256, 0, stream>>>(
                Hpart, Sd, alog2, CB);
            scan_final_k<<<(NP2 * SCAN_C + 255) / 256, 256, 0, stream>>>(
                deltab2, uzb2, ucb2, xdbc2, alog2, Dp2, Hpart, deltab2, CB);
            // accb = [y_f | y_r] @ outw2 (K=1024, fwd+rev summed in-MFMA)
            bgemm(deltab2, 1024, outw2_t + (size_t)l * 512 * 1024, 1024, nullptr,
                  accb, 512, nullptr, 0, R, 512, 1024, 0, 0);

            // x = LN(x + fwd + rev)
            ln_k<<<R, 64, 0, stream>>>(accb, x, norm1_w + l * DMODEL, norm1_b + l * DMODEL,
                                       x, xb);
            // FFN (mid reuses ucb2 as [R][512])
            bgemm(xb, 512, f1_t + (size_t)l * 512 * 512, 512, ffn_b1 + l * DMODEL,
                  nullptr, 0, ucb2, 512, R, 512, 512, 1, 0);
            bgemm(ucb2, 512, f2_t + (size_t)l * 512 * 512, 512, ffn_b2 + l * DMODEL,
                  accb, 512, nullptr, 0, R, 512, 512, 0, 0);
            ln_k<<<R, 64, 0, stream>>>(x, accb, norm2_w + l * DMODEL, norm2_b + l * DMODEL,
                                       x, xb);
        }

        ln_k<<<R, 64, 0, stream>>>(x, nullptr, normf_w, normf_b, nullptr, xb);
        bgemm(xb, 512, proj_t, 512, proj_b, xdbc2, 96, nullptr, 0, R, 96, 512, 0, 0);
        final_k<<<(CB * LFUT * NVARS + 255) / 256, 256, 0, stream>>>(
            xdbc2, meanb, stdb, out, b0, CB);
    }
}

// Round 14
// 2400.892 us; speedup vs baseline: 1.2441x; 1.0543x over previous
//
#include <hip/hip_runtime.h>
#include <math.h>

#define BATCH 32
#define LHIST 96
#define NVARS 862
#define LFUT  96
#define DMODEL 512
#define DINNER 512
#define DSTATE 32
#define DTRANK 32
#define SCAN_C 16
#define SCAN_TC ((NVARS + SCAN_C - 1) / SCAN_C)   // 54

typedef short short8 __attribute__((ext_vector_type(8)));
typedef float floatx4 __attribute__((ext_vector_type(4)));
typedef unsigned short ushort;

#define LOG2E 1.44269504088896f

static __device__ __forceinline__ ushort f2b(float f) {
    unsigned u = __builtin_bit_cast(unsigned, f);
    unsigned r = (u + 0x7FFFu + ((u >> 16) & 1u)) >> 16;
    return (ushort)r;
}
static __device__ __forceinline__ float b2f(ushort h) {
    unsigned u = ((unsigned)h) << 16;
    return __builtin_bit_cast(float, u);
}

// ---------------------------------------------------------------- mean/std
__global__ void meanstd_k(const float* __restrict__ hist, ushort* __restrict__ xinb,
                          float* __restrict__ meanb, float* __restrict__ stdb,
                          int b0, int CB) {
    int idx = blockIdx.x * blockDim.x + threadIdx.x;
    if (idx >= CB * NVARS) return;
    int b = b0 + idx / NVARS, n = idx % NVARS;
    const float* p = hist + (size_t)b * LHIST * NVARS + n;
    float s = 0.f;
    for (int l = 0; l < LHIST; l++) s += p[(size_t)l * NVARS];
    float mean = s * (1.f / LHIST);
    float v = 0.f;
    for (int l = 0; l < LHIST; l++) { float d = p[(size_t)l * NVARS] - mean; v += d * d; }
    v *= (1.f / LHIST);
    float sd = sqrtf(v + 1e-5f);
    float inv = 1.f / sd;
    meanb[idx] = mean;
    stdb[idx]  = sd;
    ushort* o = xinb + (size_t)idx * LHIST;
    for (int l = 0; l < LHIST; l++) o[l] = f2b((p[(size_t)l * NVARS] - mean) * inv);
}

// ---------------------------------------------------------------- weight casts
// batched: W[P][K][N] -> Wt[P][N][K] bf16
__global__ void castT_k(const float* __restrict__ W, ushort* __restrict__ Wt,
                        int K, int N, int P) {
    size_t idx = (size_t)blockIdx.x * blockDim.x + threadIdx.x;
    if (idx >= (size_t)P * K * N) return;
    size_t kn = (size_t)K * N;
    int p = (int)(idx / kn);
    int rem = (int)(idx % kn);
    int k = rem / N, n = rem % N;
    Wt[(size_t)p * kn + (size_t)n * K + k] = f2b(W[idx]);
}

// fused-direction x-proj weights: xw2[l][n:192][k:1024], block-diagonal
__global__ void xw2_cast(const float* __restrict__ xw, ushort* __restrict__ o) {
    int idx = blockIdx.x * blockDim.x + threadIdx.x;
    if (idx >= 2 * 192 * 1024) return;
    int l = idx / (192 * 1024);
    int r = idx % (192 * 1024);
    int n = r / 1024, k = r % 1024;
    int half = (n >= 96);
    int nn = n - 96 * half;
    float v = 0.f;
    if ((k >> 9) == half)
        v = xw[((size_t)(l * 2 + half) * 512 + (k & 511)) * 96 + nn];
    o[idx] = f2b(v);
}

// fused-direction dt-proj weights: dtw2[l][n:1024][k:192], block-diagonal
__global__ void dtw2_cast(const float* __restrict__ dtw, ushort* __restrict__ o) {
    int idx = blockIdx.x * blockDim.x + threadIdx.x;
    if (idx >= 2 * 1024 * 192) return;
    int l = idx / (1024 * 192);
    int r = idx % (1024 * 192);
    int n = r / 192, k = r % 192;
    int half = n >> 9;
    int nn = n & 511;
    int kb = k - 96 * half;
    float v = 0.f;
    if (kb >= 0 && kb < 32)
        v = dtw[((size_t)(l * 2 + half) * 32 + kb) * 512 + nn];
    o[idx] = f2b(v);
}

// fused-direction out-proj weights: outw2[l][n:512][k:1024] (K-concat fwd|rev)
__global__ void outw2_cast(const float* __restrict__ ow, ushort* __restrict__ o) {
    int idx = blockIdx.x * blockDim.x + threadIdx.x;
    if (idx >= 2 * 512 * 1024) return;
    int l = idx / (512 * 1024);
    int r = idx % (512 * 1024);
    int n = r / 1024, k = r % 1024;
    int half = k >> 9;
    float v = ow[((size_t)(l * 2 + half) * 512 + (k & 511)) * 512 + n];
    o[idx] = f2b(v);
}

// ---------------------------------------------------------------- bf16 MFMA GEMM
// C[M,N] = act(A[M,K]bf16 @ Bt[N,K]^T + bias) (+C). act: 0 none, 1 relu, 2 softplus.
// Software-pipelined: LDS double buffer, 2-tile-ahead register prefetch, ONE
// barrier per K-iter. Global-load latency hides under the previous tile's
// MFMA (m97 operating point: ~3 blocks/CU, pipeline > occupancy for GEMM).
#define TBM 128
#define TBN 128
#define TBK 32

__global__ __launch_bounds__(256)
void bgemm_k(const ushort* __restrict__ A, int lda,
             const ushort* __restrict__ Bt, int ldb,
             const float* __restrict__ bias,
             float* __restrict__ C, int ldc,
             ushort* __restrict__ C2, int ldc2,
             int M, int N, int K, int act, int accum) {
    __shared__ ushort As[2][TBM][TBK];
    __shared__ ushort Bs[2][TBN][TBK];
    int tid = threadIdx.x;
    int gm0 = blockIdx.y * TBM, gn0 = blockIdx.x * TBN;
    int lane = tid & 63, w = tid >> 6;
    int wm = (w >> 1) * 64, wn = (w & 1) * 64;
    int col16 = lane & 15, quad = lane >> 4;

    floatx4 acc[4][4];
#pragma unroll
    for (int i = 0; i < 4; i++)
#pragma unroll
        for (int j = 0; j < 4; j++) acc[i][j] = (floatx4){0.f, 0.f, 0.f, 0.f};

    int srow = tid >> 2;            // 0..63
    int schunk = (tid & 3) * 8;     // k-element offset (0,8,16,24)

    // clamped loop-invariant row pointers
    const ushort* pa0 = A + (size_t)min(gm0 + srow, M - 1) * lda + schunk;
    const ushort* pa1 = A + (size_t)min(gm0 + srow + 64, M - 1) * lda + schunk;
    const ushort* pb0 = Bt + (size_t)min(gn0 + srow, N - 1) * ldb + schunk;
    const ushort* pb1 = Bt + (size_t)min(gn0 + srow + 64, N - 1) * ldb + schunk;

    int nk = K / TBK;

    // tile 0 -> regs -> LDS buf 0
    short8 ra0 = *(const short8*)pa0;
    short8 ra1 = *(const short8*)pa1;
    short8 rb0 = *(const short8*)pb0;
    short8 rb1 = *(const short8*)pb1;
    *(short8*)&As[0][srow][schunk]      = ra0;
    *(short8*)&As[0][srow + 64][schunk] = ra1;
    *(short8*)&Bs[0][srow][schunk]      = rb0;
    *(short8*)&Bs[0][srow + 64][schunk] = rb1;
    // tile 1 -> regs
    if (nk > 1) {
        ra0 = *(const short8*)(pa0 + TBK);
        ra1 = *(const short8*)(pa1 + TBK);
        rb0 = *(const short8*)(pb0 + TBK);
        rb1 = *(const short8*)(pb1 + TBK);
    }

    for (int it = 0; it < nk; it++) {
        __syncthreads();   // buf[it&1] fully written; prior reads of buf[it&1^1] drained
        int cur = it & 1;

        short8 af[4], bf[4];
#pragma unroll
        for (int mt = 0; mt < 4; mt++)
            af[mt] = *(const short8*)&As[cur][wm + mt * 16 + col16][quad * 8];
#pragma unroll
        for (int nt = 0; nt < 4; nt++)
            bf[nt] = *(const short8*)&Bs[cur][wn + nt * 16 + col16][quad * 8];

        if (it + 1 < nk) {          // staged regs (tile it+1) -> other buffer
            int nxt = cur ^ 1;
            *(short8*)&As[nxt][srow][schunk]      = ra0;
            *(short8*)&As[nxt][srow + 64][schunk] = ra1;
            *(short8*)&Bs[nxt][srow][schunk]      = rb0;
            *(short8*)&Bs[nxt][srow + 64][schunk] = rb1;
        }
        if (it + 2 < nk) {          // prefetch tile it+2 -> regs
            int k2 = (it + 2) * TBK;
            ra0 = *(const short8*)(pa0 + k2);
            ra1 = *(const short8*)(pa1 + k2);
            rb0 = *(const short8*)(pb0 + k2);
            rb1 = *(const short8*)(pb1 + k2);
        }

#pragma unroll
        for (int mt = 0; mt < 4; mt++)
#pragma unroll
            for (int nt = 0; nt < 4; nt++)
                acc[mt][nt] = __builtin_amdgcn_mfma_f32_16x16x32_bf16(
                    af[mt], bf[nt], acc[mt][nt], 0, 0, 0);
    }

    int rbase = gm0 + wm + quad * 4;
    int cbase = gn0 + wn + col16;
#pragma unroll
    for (int mt = 0; mt < 4; mt++) {
#pragma unroll
        for (int reg = 0; reg < 4; reg++) {
            int r = rbase + mt * 16 + reg;
            if (r >= M) continue;
#pragma unroll
            for (int nt = 0; nt < 4; nt++) {
                int c = cbase + nt * 16;
                if (c >= N) continue;
                float v = acc[mt][nt][reg];
                if (bias) v += bias[c];
                if (act == 1) v = fmaxf(v, 0.f);
                else if (act == 2) v = (v > 20.f) ? v : log1pf(expf(v));
                if (accum) v += C[(size_t)r * ldc + c];
                if (C)  C[(size_t)r * ldc + c] = v;
                if (C2) C2[(size_t)r * ldc2 + c] = f2b(v);
            }
        }
    }
}

// ---------------------------------------------------------------- conv+silu, both dirs
// uzb2 row: [u_f(512) | z_f(512) | u_r(512) | z_r(512)]. Writes ucb2 [R][1024]
// (col = half*512+e). rev = half.
__global__ void conv8_k(const ushort* __restrict__ uzb2, const float* __restrict__ cw2,
                        const float* __restrict__ cb2, ushort* __restrict__ ucb2, int R) {
    int idx = blockIdx.x * blockDim.x + threadIdx.x;
    if (idx >= R * 128) return;
    int m = idx >> 7;
    int c8 = (idx & 127) * 8;
    int half = c8 >> 9;
    int e0 = c8 & 511;
    int t = m % NVARS;
    const ushort* up = uzb2 + (size_t)m * 2048 + half * 1024 + e0;
    short8 cur = *(const short8*)up;
    short8 oth = (short8){0,0,0,0,0,0,0,0};
    if (!half) { if (t > 0)          oth = *(const short8*)(up - 2048); }
    else       { if (t < NVARS - 1)  oth = *(const short8*)(up + 2048); }
    const float* cw = cw2 + half * 1024;
    const float* cb = cb2 + half * 512;
    short8 res;
#pragma unroll
    for (int i = 0; i < 8; i++) {
        int e = e0 + i;
        float v = cw[e * 2] * b2f((ushort)oth[i]) + cw[e * 2 + 1] * b2f((ushort)cur[i]) + cb[e];
        float sig = 1.f / (1.f + __expf(-v));
        res[i] = (short)f2b(v * sig);
    }
    *(short8*)(ucb2 + (size_t)m * 1024 + c8) = res;
}

// ---------------------------------------------------------------- chunked scan, both dirs
// col in [0,1024): half = col>>9 (= rev direction, wave-uniform), e = col&511.
// delta bf16 deltab2[R][1024], u bf16 ucb2[R][1024], z in uzb2, B/C fp32 in
// xdbc2[R][192] (+half*96). Fast path: A[s] = -(s+1) (A_log = log(1..32) by
// construction), q=exp(-d), single power chain, NO A registers.
// launch_bounds (256,4): (256,8) forced VGPR=32 + h[32] spill (R10);
// (256,4) -> VGPR 64 no spill (R11).

static __device__ __forceinline__ bool a_is_fast(const float* A_log2, int col) {
    bool f = true;
#pragma unroll
    for (int s = 0; s < DSTATE; s++) {
        float a = -__expf(A_log2[col * DSTATE + s]);
        f = f && (fabsf(a + (float)(s + 1)) < 1e-3f * (s + 1));
    }
    return f;
}

// Pass A: local scan from h=0 -> Hpart[c][s][be], Sd[c][be]
__global__ __launch_bounds__(256, 4)
void scan_part_k(const ushort* __restrict__ deltab2, const ushort* __restrict__ ucb2,
                 const float* __restrict__ xdbc2, const float* __restrict__ alog2,
                 float* __restrict__ Hpart, float* __restrict__ Sd, int CB) {
    int NP2 = CB * 1024;
    int idx = blockIdx.x * blockDim.x + threadIdx.x;
    if (idx >= NP2 * SCAN_C) return;
    int c = idx / NP2, be = idx % NP2;
    int b = be >> 10, col = be & 1023;
    int rv = col >> 9;

    float h[DSTATE];
#pragma unroll
    for (int s = 0; s < DSTATE; s++) h[s] = 0.f;
    float sd = 0.f;
    int tau1 = min((c + 1) * SCAN_TC, NVARS);
    if (a_is_fast(alog2, col)) {
        for (int tau = c * SCAN_TC; tau < tau1; tau++) {
            int t = rv ? (NVARS - 1 - tau) : tau;
            size_t m = (size_t)b * NVARS + t;
            float d  = b2f(deltab2[m * 1024 + col]);
            float uv = b2f(ucb2[m * 1024 + col]);
            float du = d * uv;
            sd += d;
            const float4* Bp4 = (const float4*)(xdbc2 + m * 192 + rv * 96 + DTRANK);
            float q = __expf(-d), pw = q;
#pragma unroll
            for (int g = 0; g < 8; g++) {
                float4 bv = Bp4[g];
                h[4*g+0] = pw * h[4*g+0] + du * bv.x; pw *= q;
                h[4*g+1] = pw * h[4*g+1] + du * bv.y; pw *= q;
                h[4*g+2] = pw * h[4*g+2] + du * bv.z; pw *= q;
                h[4*g+3] = pw * h[4*g+3] + du * bv.w; if (g < 7) pw *= q;
            }
        }
    } else {
        for (int tau = c * SCAN_TC; tau < tau1; tau++) {
            int t = rv ? (NVARS - 1 - tau) : tau;
            size_t m = (size_t)b * NVARS + t;
            float d  = b2f(deltab2[m * 1024 + col]);
            float uv = b2f(ucb2[m * 1024 + col]);
            float du = d * uv;
            sd += d;
            const float* Bp = xdbc2 + m * 192 + rv * 96 + DTRANK;
#pragma unroll
            for (int s = 0; s < DSTATE; s++) {
                float a2 = -__expf(alog2[col * DSTATE + s]) * LOG2E;
                h[s] = exp2f(d * a2) * h[s] + du * Bp[s];
            }
        }
    }
    Sd[(size_t)c * NP2 + be] = sd;
#pragma unroll
    for (int s = 0; s < DSTATE; s++)
        Hpart[((size_t)c * DSTATE + s) * NP2 + be] = h[s];
}

// Pass B: thread per (s, be); carry across chunks; Hpart -> carry-in (in place).
__global__ __launch_bounds__(256)
void scan_carry_k(float* __restrict__ Hpart, const float* __restrict__ Sd,
                  const float* __restrict__ alog2, int CB) {
    int NP2 = CB * 1024;
    int idx = blockIdx.x * blockDim.x + threadIdx.x;
    if (idx >= NP2 * DSTATE) return;
    int s = idx / NP2, be = idx % NP2;
    int col = be & 1023;
    float a2 = -__expf(alog2[col * DSTATE + s]) * LOG2E;
    float carry = 0.f;
    for (int c = 0; c < SCAN_C; c++) {
        float sd = Sd[(size_t)c * NP2 + be];
        size_t off = ((size_t)c * DSTATE + s) * NP2 + be;
        float hp = Hpart[off];
        Hpart[off] = carry;
        carry = hp + exp2f(a2 * sd) * carry;
    }
}

// Pass C: rerun local scan seeded with carry-in; emit gated y as bf16.
// yb may alias deltab2 (same-element read-before-write, chunk-disjoint m).
__global__ __launch_bounds__(256, 4)
void scan_final_k(const ushort* __restrict__ deltab2, const ushort* __restrict__ uzb2,
                  const ushort* __restrict__ ucb2, const float* __restrict__ xdbc2,
                  const float* __restrict__ alog2, const float* __restrict__ Dp2,
                  const float* __restrict__ CarryIn, ushort* __restrict__ yb, int CB) {
    int NP2 = CB * 1024;
    int idx = blockIdx.x * blockDim.x + threadIdx.x;
    if (idx >= NP2 * SCAN_C) return;
    int c = idx / NP2, be = idx % NP2;
    int b = be >> 10, col = be & 1023;
    int rv = col >> 9;

    float h[DSTATE];
#pragma unroll
    for (int s = 0; s < DSTATE; s++)
        h[s] = CarryIn[((size_t)c * DSTATE + s) * NP2 + be];
    float Dv = Dp2[col];
    int tau1 = min((c + 1) * SCAN_TC, NVARS);
    if (a_is_fast(alog2, col)) {
        for (int tau = c * SCAN_TC; tau < tau1; tau++) {
            int t = rv ? (NVARS - 1 - tau) : tau;
            size_t m = (size_t)b * NVARS + t;
            float d  = b2f(deltab2[m * 1024 + col]);
            float zz = b2f(uzb2[m * 2048 + rv * 1024 + 512 + (col & 511)]);
            float uv = b2f(ucb2[m * 1024 + col]);
            float du = d * uv;
            const float4* Bp4 = (const float4*)(xdbc2 + m * 192 + rv * 96 + DTRANK);
            const float4* Cp4 = Bp4 + 8;
            float q = __expf(-d), pw = q;
            float accv = 0.f;
#pragma unroll
            for (int g = 0; g < 8; g++) {
                float4 bv = Bp4[g];
                float4 cv = Cp4[g];
                h[4*g+0] = pw * h[4*g+0] + du * bv.x; accv += h[4*g+0] * cv.x; pw *= q;
                h[4*g+1] = pw * h[4*g+1] + du * bv.y; accv += h[4*g+1] * cv.y; pw *= q;
                h[4*g+2] = pw * h[4*g+2] + du * bv.z; accv += h[4*g+2] * cv.z; pw *= q;
                h[4*g+3] = pw * h[4*g+3] + du * bv.w; accv += h[4*g+3] * cv.w;
                if (g < 7) pw *= q;
            }
            float sig = 1.f / (1.f + __expf(-zz));
            yb[m * 1024 + col] = f2b((accv + uv * Dv) * (zz * sig));
        }
    } else {
        for (int tau = c * SCAN_TC; tau < tau1; tau++) {
            int t = rv ? (NVARS - 1 - tau) : tau;
            size_t m = (size_t)b * NVARS + t;
            float d  = b2f(deltab2[m * 1024 + col]);
            float zz = b2f(uzb2[m * 2048 + rv * 1024 + 512 + (col & 511)]);
            float uv = b2f(ucb2[m * 1024 + col]);
            float du = d * uv;
            const float* Bp = xdbc2 + m * 192 + rv * 96 + DTRANK;
            const float* Cp = Bp + DSTATE;
            float accv = 0.f;
#pragma unroll
            for (int s = 0; s < DSTATE; s++) {
                float a2 = -__expf(alog2[col * DSTATE + s]) * LOG2E;
                h[s] = exp2f(d * a2) * h[s] + du * Bp[s];
                accv += h[s] * Cp[s];
            }
            float sig = 1.f / (1.f + __expf(-zz));
            yb[m * 1024 + col] = f2b((accv + uv * Dv) * (zz * sig));
        }
    }
}

// ---------------------------------------------------------------- layernorm
__global__ __launch_bounds__(64)
void ln_k(const float* __restrict__ in1, const float* __restrict__ in2,
          const float* __restrict__ w, const float* __restrict__ b,
          float* __restrict__ out, ushort* __restrict__ outb) {
    int row = blockIdx.x;
    int lane = threadIdx.x;
    const float* p1 = in1 + (size_t)row * DMODEL;
    const float* p2 = in2 ? in2 + (size_t)row * DMODEL : nullptr;
    float v[8];
#pragma unroll
    for (int i = 0; i < 8; i++) {
        int c = lane + i * 64;
        v[i] = p1[c];
        if (p2) v[i] += p2[c];
    }
    float s = 0.f;
#pragma unroll
    for (int i = 0; i < 8; i++) s += v[i];
#pragma unroll
    for (int off = 32; off >= 1; off >>= 1) s += __shfl_xor(s, off);
    float mean = s * (1.f / DMODEL);
    float q = 0.f;
#pragma unroll
    for (int i = 0; i < 8; i++) { float d = v[i] - mean; q += d * d; }
#pragma unroll
    for (int off = 32; off >= 1; off >>= 1) q += __shfl_xor(q, off);
    float rs = rsqrtf(q * (1.f / DMODEL) + 1e-5f);
#pragma unroll
    for (int i = 0; i < 8; i++) {
        int c = lane + i * 64;
        float o = (v[i] - mean) * rs * w[c] + b[c];
        if (out)  out[(size_t)row * DMODEL + c] = o;
        if (outb) outb[(size_t)row * DMODEL + c] = f2b(o);
    }
}

// ---------------------------------------------------------------- de-norm + transpose
__global__ void final_k(const float* __restrict__ dec, const float* __restrict__ meanb,
                        const float* __restrict__ stdb, float* __restrict__ out,
                        int b0, int CB) {
    int idx = blockIdx.x * blockDim.x + threadIdx.x;
    if (idx >= CB * LFUT * NVARS) return;
    int n = idx % NVARS;
    int r = idx / NVARS;
    int l = r % LFUT;
    int bl = r / LFUT;
    int tok = bl * NVARS + n;
    out[(size_t)((b0 + bl) * LFUT + l) * NVARS + n] =
        dec[(size_t)tok * LFUT + l] * stdb[tok] + meanb[tok];
}

// ---------------------------------------------------------------- launch
extern "C" void kernel_launch(void* const* d_in, const int* in_sizes, int n_in,
                              void* d_out, int out_size, void* d_ws, size_t ws_size,
                              hipStream_t stream) {
    const float* hist    = (const float*)d_in[0];
    const float* emb_w   = (const float*)d_in[1];
    const float* emb_b   = (const float*)d_in[2];
    const float* m_in_w  = (const float*)d_in[3];
    const float* m_conv_w= (const float*)d_in[4];
    const float* m_conv_b= (const float*)d_in[5];
    const float* m_x_w   = (const float*)d_in[6];
    const float* m_dt_w  = (const float*)d_in[7];
    const float* m_dt_b  = (const float*)d_in[8];
    const float* m_A_log = (const float*)d_in[9];
    const float* m_D     = (const float*)d_in[10];
    const float* m_out_w = (const float*)d_in[11];
    const float* ffn_w1  = (const float*)d_in[12];
    const float* ffn_b1  = (const float*)d_in[13];
    const float* ffn_w2  = (const float*)d_in[14];
    const float* ffn_b2  = (const float*)d_in[15];
    const float* norm1_w = (const float*)d_in[16];
    const float* norm1_b = (const float*)d_in[17];
    const float* norm2_w = (const float*)d_in[18];
    const float* norm2_b = (const float*)d_in[19];
    const float* normf_w = (const float*)d_in[20];
    const float* normf_b = (const float*)d_in[21];
    const float* proj_w  = (const float*)d_in[22];
    const float* proj_b  = (const float*)d_in[23];

    float* out = (float*)d_out;
    float* ws  = (float*)d_ws;

    // bf16 weight pool elems
    const size_t WTSE = 4u*1024*512      // in_w
                      + 2u*512*1024      // outw2 (K-concat)
                      + 2u*512*512 + 2u*512*512   // ffn1/ffn2
                      + 512u*96          // emb
                      + 2u*192*1024      // xw2 (block-diag)
                      + 2u*1024*192      // dtw2 (block-diag)
                      + 512u*96;         // proj

    // adaptive CB so footprint fits ws_size
    int CB = BATCH;
    for (;;) {
        size_t R = (size_t)CB * NVARS, NP2 = (size_t)CB * 1024;
        size_t Rp = (R + 3) & ~3ull;
        size_t fl = R * 1216 + 2 * Rp + (size_t)SCAN_C * 33 * NP2;  // fp32 elems
        size_t us = R * 4896 + WTSE;                                 // bf16 elems
        if (fl * 4 + us * 2 + 1024 <= ws_size || CB == 1) break;
        CB >>= 1;
    }
    const int R   = CB * NVARS;
    const int NP2 = CB * 1024;
    const size_t Rp = ((size_t)R + 3) & ~3ull;

    float* x     = ws;                                     // [R][512]
    float* accb  = x + (size_t)R * 512;                    // [R][512]
    float* xdbc2 = accb + (size_t)R * 512;                 // [R][192] (later dec[R][96])
    float* meanb = xdbc2 + (size_t)R * 192;                // [Rp]
    float* stdb  = meanb + Rp;                             // [Rp]
    float* Hpart = stdb + Rp;                              // [C][32][NP2]
    float* Sd    = Hpart + (size_t)SCAN_C * DSTATE * NP2;  // [C][NP2]
    ushort* xb      = (ushort*)(Sd + (size_t)SCAN_C * NP2); // [R][512]
    ushort* uzb2    = xb + (size_t)R * 512;                 // [R][2048]
    ushort* ucb2    = uzb2 + (size_t)R * 2048;              // [R][1024] (ffn-mid reuse)
    ushort* deltab2 = ucb2 + (size_t)R * 1024;              // [R][1024] (y2 aliased)
    ushort* xinb    = deltab2 + (size_t)R * 1024;           // [R][96]
    ushort* xdbc2b  = xinb + (size_t)R * 96;                // [R][192]
    ushort* wts     = xdbc2b + (size_t)R * 192;

    ushort *inw_t, *outw2_t, *f1_t, *f2_t, *emb_t, *xw2_t, *dtw2_t, *proj_t;
    {
        ushort* p = wts;
        inw_t   = p; p += (size_t)4 * 1024 * 512;
        outw2_t = p; p += (size_t)2 * 512 * 1024;
        f1_t    = p; p += (size_t)2 * 512 * 512;
        f2_t    = p; p += (size_t)2 * 512 * 512;
        emb_t   = p; p += (size_t)512 * 96;
        xw2_t   = p; p += (size_t)2 * 192 * 1024;
        dtw2_t  = p; p += (size_t)2 * 1024 * 192;
        proj_t  = p;
    }

    // weight casts (8 dispatches)
    castT_k<<<(4 * 512 * 1024 + 255) / 256, 256, 0, stream>>>(m_in_w, inw_t, 512, 1024, 4);
    outw2_cast<<<(2 * 512 * 1024 + 255) / 256, 256, 0, stream>>>(m_out_w, outw2_t);
    castT_k<<<(2 * 512 * 512 + 255) / 256, 256, 0, stream>>>(ffn_w1, f1_t, 512, 512, 2);
    castT_k<<<(2 * 512 * 512 + 255) / 256, 256, 0, stream>>>(ffn_w2, f2_t, 512, 512, 2);
    castT_k<<<(96 * 512 + 255) / 256, 256, 0, stream>>>(emb_w, emb_t, 96, 512, 1);
    xw2_cast<<<(2 * 192 * 1024 + 255) / 256, 256, 0, stream>>>(m_x_w, xw2_t);
    dtw2_cast<<<(2 * 1024 * 192 + 255) / 256, 256, 0, stream>>>(m_dt_w, dtw2_t);
    castT_k<<<(512 * 96 + 255) / 256, 256, 0, stream>>>(proj_w, proj_t, 512, 96, 1);

    auto bgemm = [&](const ushort* A, int lda, const ushort* Bt, int ldb,
                     const float* bias, float* C, int ldc, ushort* C2, int ldc2,
                     int M, int N, int K, int act, int accum) {
        dim3 grid((N + TBN - 1) / TBN, (M + TBM - 1) / TBM);
        bgemm_k<<<grid, 256, 0, stream>>>(A, lda, Bt, ldb, bias, C, ldc, C2, ldc2,
                                          M, N, K, act, accum);
    };

    for (int b0 = 0; b0 < BATCH; b0 += CB) {
        meanstd_k<<<(R + 255) / 256, 256, 0, stream>>>(hist, xinb, meanb, stdb, b0, CB);
        bgemm(xinb, 96, emb_t, 96, emb_b, x, 512, xb, 512, R, 512, 96, 0, 0);

        for (int l = 0; l < 2; l++) {
            const float* cw2   = m_conv_w + (size_t)l * 2048;        // [2][512][2]
            const float* cb2   = m_conv_b + (size_t)l * 1024;        // [2][512]
            const float* dtb2  = m_dt_b  + (size_t)l * 1024;         // [2][512]
            const float* alog2 = m_A_log + (size_t)l * 2 * 512 * 32; // [1024][32]
            const float* Dp2   = m_D     + (size_t)l * 1024;         // [1024]

            // uzb2 = bf16(x @ [in_w_f | in_w_r])   [R][2048]
            bgemm(xb, 512, inw_t + (size_t)(2 * l) * 1024 * 512, 512, nullptr,
                  nullptr, 0, uzb2, 2048, R, 2048, 512, 0, 0);
            // ucb2 = bf16(silu(conv(u))), both directions
            conv8_k<<<(R * 128 + 255) / 256, 256, 0, stream>>>(uzb2, cw2, cb2, ucb2, R);
            // xdbc2 = ucb2 @ xw2 (block-diag), fp32 + bf16
            bgemm(ucb2, 1024, xw2_t + (size_t)l * 192 * 1024, 1024, nullptr,
                  xdbc2, 192, xdbc2b, 192, R, 192, 1024, 0, 0);
            // deltab2 = bf16(softplus(xdbc2b @ dtw2 + dtb2)), both dirs
            bgemm(xdbc2b, 192, dtw2_t + (size_t)l * 1024 * 192, 192, dtb2,
                  nullptr, 0, deltab2, 1024, R, 1024, 192, 2, 0);
            // chunked scan, both dirs (y2 aliases deltab2)
            scan_part_k<<<(NP2 * SCAN_C + 255) / 256, 256, 0, stream>>>(
                deltab2, ucb2, xdbc2, alog2, Hpart, Sd, CB);
            scan_carry_k<<<(NP2 * DSTATE + 255) / 256, 256, 0, stream>>>(
                Hpart, Sd, alog2, CB);
            scan_final_k<<<(NP2 * SCAN_C + 255) / 256, 256, 0, stream>>>(
                deltab2, uzb2, ucb2, xdbc2, alog2, Dp2, Hpart, deltab2, CB);
            // accb = [y_f | y_r] @ outw2 (K=1024, fwd+rev summed in-MFMA)
            bgemm(deltab2, 1024, outw2_t + (size_t)l * 512 * 1024, 1024, nullptr,
                  accb, 512, nullptr, 0, R, 512, 1024, 0, 0);

            // x = LN(x + fwd + rev)
            ln_k<<<R, 64, 0, stream>>>(accb, x, norm1_w + l * DMODEL, norm1_b + l * DMODEL,
                                       x, xb);
            // FFN (mid reuses ucb2 as [R][512])
            bgemm(xb, 512, f1_t + (size_t)l * 512 * 512, 512, ffn_b1 + l * DMODEL,
                  nullptr, 0, ucb2, 512, R, 512, 512, 1, 0);
            bgemm(ucb2, 512, f2_t + (size_t)l * 512 * 512, 512, ffn_b2 + l * DMODEL,
                  accb, 512, nullptr, 0, R, 512, 512, 0, 0);
            ln_k<<<R, 64, 0, stream>>>(x, accb, norm2_w + l * DMODEL, norm2_b + l * DMODEL,
                                       x, xb);
        }

        ln_k<<<R, 64, 0, stream>>>(x, nullptr, normf_w, normf_b, nullptr, xb);
        bgemm(xb, 512, proj_t, 512, proj_b, xdbc2, 96, nullptr, 0, R, 96, 512, 0, 0);
        final_k<<<(CB * LFUT * NVARS + 255) / 256, 256, 0, stream>>>(
            xdbc2, meanb, stdb, out, b0, CB);
    }
}